// Round 1
// baseline (102.322 us; speedup 1.0000x reference)
//
#include <hip/hip_runtime.h>

// Chamfer distance, B=16, N=M=4096, D=3, fp32.
// loss = sum_b mean_n min_m d2(src,tgt) + sum_b mean_m min_n d2(tgt,src)
//      = (sum of all 2*16*4096 directional mins) / 4096
//
// d2 = |s|^2 + |t|^2 - 2 s.t = 2*( f + (e - s.t) ),  f=0.5|s|^2, e=0.5|t|^2
// Per pair: 3 fma (neg-s dot t, seeded with e) + 1 min = 4 VALU ops.

#define BATCH   16
#define NPTS    4096
#define TPB     256
#define PPT     8                   // "query" points per thread
#define CHUNK   (PPT * TPB)         // 2048 query points per block
#define NCHUNK  (NPTS / CHUNK)      // 2
#define SEG     256                 // target points staged per block
#define NSEG    (NPTS / SEG)        // 16

__global__ __launch_bounds__(TPB) void chamfer_min_kernel(
    const float* __restrict__ src, const float* __restrict__ tgt,
    unsigned int* __restrict__ mins)
{
    __shared__ float4 sh[SEG];      // (x, y, z, 0.5*|t|^2)

    int bx = blockIdx.x;
    const int seg   = bx & (NSEG - 1);   bx >>= 4;
    const int chunk = bx & (NCHUNK - 1); bx >>= 1;
    const int b     = bx & (BATCH - 1);  bx >>= 4;
    const int dir   = bx;                 // 0: min over tgt for src pts; 1: swapped

    const float* Aset = dir ? tgt : src;  // query points
    const float* Bset = dir ? src : tgt;  // target points
    const float* Abase = Aset + (size_t)b * NPTS * 3;
    const float* Bbase = Bset + (size_t)b * NPTS * 3;

    const int t = threadIdx.x;

    // Stage SEG target points (one per thread) with precomputed 0.5*|t|^2.
    {
        int p = seg * SEG + t;
        float x = Bbase[3 * p + 0];
        float y = Bbase[3 * p + 1];
        float z = Bbase[3 * p + 2];
        sh[t] = make_float4(x, y, z, 0.5f * (x * x + y * y + z * z));
    }

    // Load PPT query points per thread (stride TPB for coalescing), negate.
    float nsx[PPT], nsy[PPT], nsz[PPT], f[PPT], mn[PPT];
#pragma unroll
    for (int k = 0; k < PPT; k++) {
        int p = chunk * CHUNK + k * TPB + t;
        float x = Abase[3 * p + 0];
        float y = Abase[3 * p + 1];
        float z = Abase[3 * p + 2];
        nsx[k] = -x; nsy[k] = -y; nsz[k] = -z;
        f[k] = 0.5f * (x * x + y * y + z * z);
        mn[k] = 1e30f;
    }

    __syncthreads();

    // Inner loop: 4 target points per iteration (broadcast LDS b128 reads).
    for (int m = 0; m < SEG; m += 4) {
        float4 q0 = sh[m + 0];
        float4 q1 = sh[m + 1];
        float4 q2 = sh[m + 2];
        float4 q3 = sh[m + 3];
#pragma unroll
        for (int k = 0; k < PPT; k++) {
            float a0 = fmaf(nsz[k], q0.z, q0.w);
            a0 = fmaf(nsy[k], q0.y, a0);
            a0 = fmaf(nsx[k], q0.x, a0);
            float a1 = fmaf(nsz[k], q1.z, q1.w);
            a1 = fmaf(nsy[k], q1.y, a1);
            a1 = fmaf(nsx[k], q1.x, a1);
            float a2 = fmaf(nsz[k], q2.z, q2.w);
            a2 = fmaf(nsy[k], q2.y, a2);
            a2 = fmaf(nsx[k], q2.x, a2);
            float a3 = fmaf(nsz[k], q3.z, q3.w);
            a3 = fmaf(nsy[k], q3.y, a3);
            a3 = fmaf(nsx[k], q3.x, a3);
            // shallow min tree keeps the mn[k] dep-chain to 1 min per iter
            mn[k] = fminf(mn[k], fminf(fminf(a0, a1), fminf(a2, a3)));
        }
    }

    // Epilogue: clamp (monotone, commutes with min) and merge across segments.
    unsigned int* outp = mins + (size_t)dir * (BATCH * NPTS)
                              + (size_t)b * NPTS + chunk * CHUNK;
#pragma unroll
    for (int k = 0; k < PPT; k++) {
        float d2 = 2.0f * (mn[k] + f[k]);
        d2 = fmaxf(d2, 0.0f);
        atomicMin(&outp[k * TPB + t], __float_as_uint(d2));
    }
}

#define TOTAL_MINS (2 * BATCH * NPTS)

__global__ __launch_bounds__(256) void chamfer_reduce_kernel(
    const unsigned int* __restrict__ mins, float* __restrict__ out)
{
    float s = 0.0f;
    for (int idx = blockIdx.x * blockDim.x + threadIdx.x; idx < TOTAL_MINS;
         idx += gridDim.x * blockDim.x) {
        s += __uint_as_float(mins[idx]);
    }
#pragma unroll
    for (int off = 32; off > 0; off >>= 1) s += __shfl_down(s, off, 64);
    __shared__ float wsum[4];
    int lane = threadIdx.x & 63;
    int w = threadIdx.x >> 6;
    if (lane == 0) wsum[w] = s;
    __syncthreads();
    if (threadIdx.x == 0) {
        float tot = wsum[0] + wsum[1] + wsum[2] + wsum[3];
        atomicAdd(out, tot * (1.0f / (float)NPTS));
    }
}

extern "C" void kernel_launch(void* const* d_in, const int* in_sizes, int n_in,
                              void* d_out, int out_size, void* d_ws, size_t ws_size,
                              hipStream_t stream)
{
    const float* src = (const float*)d_in[0];
    const float* tgt = (const float*)d_in[1];
    float* out = (float*)d_out;
    unsigned int* mins = (unsigned int*)d_ws;

    // 0xFFFFFFFF as uint > any finite positive float's bits -> acts as +inf
    // under unsigned atomicMin on non-negative floats.
    hipMemsetAsync(mins, 0xFF, (size_t)TOTAL_MINS * sizeof(unsigned int), stream);
    hipMemsetAsync(out, 0, sizeof(float), stream);

    dim3 grid(2 * BATCH * NCHUNK * NSEG);   // 1024 blocks
    chamfer_min_kernel<<<grid, TPB, 0, stream>>>(src, tgt, mins);

    chamfer_reduce_kernel<<<128, 256, 0, stream>>>(mins, out);
}